// Round 1
// baseline (378.003 us; speedup 1.0000x reference)
//
#include <hip/hip_runtime.h>

#define NTOK 2304   // 48*48 tokens
#define NH 12
#define HD 64

typedef __attribute__((ext_vector_type(8))) short bf16x8;
typedef __attribute__((ext_vector_type(4))) float f32x4;

__device__ __forceinline__ unsigned short f2bf(float f){
  union { float f; unsigned u; } v; v.f = f;
  unsigned r = v.u + 0x7fffu + ((v.u >> 16) & 1u);
  return (unsigned short)(r >> 16);
}
__device__ __forceinline__ float bf2f(unsigned short h){
  union { unsigned u; float f; } v; v.u = ((unsigned)h) << 16;
  return v.f;
}
__device__ __forceinline__ void gload_lds16(const void* g, void* lds){
  __builtin_amdgcn_global_load_lds(
    (const __attribute__((address_space(1))) unsigned int*)g,
    (__attribute__((address_space(3))) unsigned int*)lds, 16, 0, 0);
}

// ---------------- fp32 -> bf16 convert ----------------
__global__ __launch_bounds__(256) void cvt_f32_bf16(const float* __restrict__ src,
                                                    unsigned short* __restrict__ dst, int n4){
  int i = blockIdx.x * 256 + threadIdx.x;
  if (i >= n4) return;
  float4 v = ((const float4*)src)[i];
  union { unsigned short u[4]; unsigned long long ll; } o;
  o.u[0] = f2bf(v.x); o.u[1] = f2bf(v.y); o.u[2] = f2bf(v.z); o.u[3] = f2bf(v.w);
  ((unsigned long long*)dst)[i] = o.ll;
}

// ---------------- LoRA t = x @ A^T  (t[3][2304][4]) ----------------
__global__ __launch_bounds__(256) void lora_t_kernel(const float* __restrict__ x,
    const float* __restrict__ Aq, const float* __restrict__ Ak, const float* __restrict__ Av,
    float* __restrict__ t){
  int wave = (blockIdx.x * 256 + threadIdx.x) >> 6;   // token
  int lane = threadIdx.x & 63;
  if (wave >= NTOK) return;
  const float* xr = x + (size_t)wave * 768;
  float part[12];
  #pragma unroll
  for (int j = 0; j < 12; j++) part[j] = 0.f;
  for (int k = lane; k < 768; k += 64){
    float xv = xr[k];
    #pragma unroll
    for (int r = 0; r < 4; r++){
      part[r]     += xv * Aq[r*768 + k];
      part[4 + r] += xv * Ak[r*768 + k];
      part[8 + r] += xv * Av[r*768 + k];
    }
  }
  #pragma unroll
  for (int j = 0; j < 12; j++){
    float v = part[j];
    #pragma unroll
    for (int off = 32; off; off >>= 1) v += __shfl_xor(v, off);
    if (lane == 0){
      int mat = j >> 2, r = j & 3;
      t[((size_t)mat * NTOK + wave) * 4 + r] = v;
    }
  }
}

// ---------------- fused qkv GEMM (+bias +LoRA, writes q(scaled),k,vT) ----------------
__global__ __launch_bounds__(256) void qkv_gemm(
    const unsigned short* __restrict__ xg,   // [2304][768] bf16
    const unsigned short* __restrict__ wg,   // [2304][768] bf16
    const float* __restrict__ bias,          // [2304]
    const float* __restrict__ t,             // [3][2304][4]
    const float* __restrict__ Bq, const float* __restrict__ Bk, const float* __restrict__ Bv, // [768][4]
    unsigned short* __restrict__ qo,         // [12][2304][64]  (pre-scaled by 0.125)
    unsigned short* __restrict__ ko,         // [12][2304][64]
    unsigned short* __restrict__ vT)         // [12][64][2304]
{
  __shared__ short As[128*64];
  __shared__ short Bs[128*64];
  const int tid = threadIdx.x;
  const int lane = tid & 63;
  const int wv = tid >> 6;
  const int r = lane & 15, g = lane >> 4;
  const int wm = (wv >> 1) * 64, wn = (wv & 1) * 64;
  const int m0 = blockIdx.y * 128, n0 = blockIdx.x * 128;

  f32x4 acc[4][4];
  #pragma unroll
  for (int i = 0; i < 4; i++)
    #pragma unroll
    for (int j = 0; j < 4; j++) acc[i][j] = (f32x4){0.f, 0.f, 0.f, 0.f};

  for (int k0 = 0; k0 < 768; k0 += 64){
    __syncthreads();
    #pragma unroll
    for (int it = 0; it < 4; it++){
      int f = it * 256 + tid;
      int row = f >> 3, u = f & 7;
      int us = ((u ^ (row & 7)) << 3);
      gload_lds16(xg + (size_t)(m0 + row) * 768 + k0 + us, &As[f * 8]);
      gload_lds16(wg + (size_t)(n0 + row) * 768 + k0 + us, &Bs[f * 8]);
    }
    __syncthreads();
    #pragma unroll
    for (int ks = 0; ks < 2; ks++){
      bf16x8 af[4], bfr[4];
      #pragma unroll
      for (int mt = 0; mt < 4; mt++){
        int row = wm + mt * 16 + r;
        af[mt] = *(const bf16x8*)&As[row * 64 + ((((ks << 2) | g) ^ (r & 7)) << 3)];
      }
      #pragma unroll
      for (int nt = 0; nt < 4; nt++){
        int row = wn + nt * 16 + r;
        bfr[nt] = *(const bf16x8*)&Bs[row * 64 + ((((ks << 2) | g) ^ (r & 7)) << 3)];
      }
      #pragma unroll
      for (int mt = 0; mt < 4; mt++)
        #pragma unroll
        for (int nt = 0; nt < 4; nt++)
          acc[mt][nt] = __builtin_amdgcn_mfma_f32_16x16x32_bf16(af[mt], bfr[nt], acc[mt][nt], 0, 0, 0);
    }
  }

  const int part = n0 / 768;
  const float* Bl = (part == 0) ? Bq : ((part == 1) ? Bk : Bv);
  const float* tp = t + (size_t)part * NTOK * 4;
  #pragma unroll
  for (int mt = 0; mt < 4; mt++){
    #pragma unroll
    for (int reg = 0; reg < 4; reg++){
      int row_m = m0 + wm + mt * 16 + g * 4 + reg;
      float4 tv = *(const float4*)&tp[row_m * 4];
      #pragma unroll
      for (int nt = 0; nt < 4; nt++){
        int col = n0 + wn + nt * 16 + r;
        int cc = col - part * 768;
        float4 bw = *(const float4*)&Bl[cc * 4];
        float val = acc[mt][nt][reg] + bias[col]
                  + 0.25f * (tv.x * bw.x + tv.y * bw.y + tv.z * bw.z + tv.w * bw.w);
        int head = cc >> 6, d = cc & 63;
        if (part == 0)      qo[((size_t)head * NTOK + row_m) * 64 + d] = f2bf(val * 0.125f);
        else if (part == 1) ko[((size_t)head * NTOK + row_m) * 64 + d] = f2bf(val);
        else                vT[((size_t)head * 64 + d) * NTOK + row_m] = f2bf(val);
      }
    }
  }
}

// ---------------- rel_h / rel_w precompute ----------------
// rel_h[head][i][kh] = q_unscaled[head][i] . rel_pos_h[ih - kh + 47]   (q stored scaled -> *8)
__global__ __launch_bounds__(256) void rel_kernel(
    const unsigned short* __restrict__ qg, const float* __restrict__ rph, const float* __restrict__ rpw,
    float* __restrict__ rel_h, float* __restrict__ rel_w){
  int ih = blockIdx.x, head = blockIdx.y;
  __shared__ float qs[48 * 64];
  __shared__ float hs[48 * 64];
  __shared__ float wsm[95 * 64];
  for (int idx = threadIdx.x; idx < 48 * 64; idx += 256){
    qs[idx] = bf2f(qg[((size_t)head * NTOK + ih * 48) * 64 + idx]);
    hs[idx] = rph[ih * 64 + idx];
  }
  for (int idx = threadIdx.x; idx < 95 * 64; idx += 256) wsm[idx] = rpw[idx];
  __syncthreads();
  for (int idx = threadIdx.x; idx < 48 * 96; idx += 256){
    int w = idx / 96, c = idx % 96;
    const float4* q4 = (const float4*)&qs[w * 64];
    const float4* r4 = (c < 48) ? (const float4*)&hs[(47 - c) * 64]
                                : (const float4*)&wsm[(w - (c - 48) + 47) * 64];
    float s = 0.f;
    #pragma unroll
    for (int d = 0; d < 16; d++){
      float4 a = q4[d], b = r4[d];
      s += a.x * b.x + a.y * b.y + a.z * b.z + a.w * b.w;
    }
    s *= 8.f;  // undo q pre-scale
    int gi = head * NTOK + ih * 48 + w;
    if (c < 48) rel_h[(size_t)gi * 48 + c] = s;
    else        rel_w[(size_t)gi * 48 + (c - 48)] = s;
  }
}

// ---------------- flash attention with rel-pos bias ----------------
__global__ __launch_bounds__(256) void attn_kernel(
    const unsigned short* __restrict__ qg,   // [12][2304][64] scaled
    const unsigned short* __restrict__ kg,   // [12][2304][64]
    const unsigned short* __restrict__ vT,   // [12][64][2304]
    const float* __restrict__ rel_h,         // [12][2304][48]
    const float* __restrict__ rel_w,         // [12][2304][48]
    unsigned short* __restrict__ ao)         // [2304][768]
{
  __shared__ float rel_s[128 * 96];
  __shared__ unsigned short P_lds[4 * 32 * 64];
  const int head = blockIdx.y;
  const int q0 = blockIdx.x * 128;
  const int tid = threadIdx.x, lane = tid & 63, wv = tid >> 6;
  const int r = lane & 15, g = lane >> 4;

  for (int idx = tid; idx < 128 * 96; idx += 256){
    int i = idx / 96, c = idx % 96;
    int token = head * NTOK + q0 + i;
    rel_s[idx] = (c < 48) ? rel_h[(size_t)token * 48 + c] : rel_w[(size_t)token * 48 + (c - 48)];
  }
  __syncthreads();

  const int qrow = q0 + wv * 32;
  bf16x8 qf[2][2];
  #pragma unroll
  for (int mt = 0; mt < 2; mt++)
    #pragma unroll
    for (int ks = 0; ks < 2; ks++)
      qf[mt][ks] = *(const bf16x8*)&qg[((size_t)head * NTOK + qrow + mt * 16 + r) * 64 + ks * 32 + g * 8];

  f32x4 Oa[2][4];
  float mrun[2][4], lrun[2][4];
  #pragma unroll
  for (int mt = 0; mt < 2; mt++){
    #pragma unroll
    for (int dt = 0; dt < 4; dt++) Oa[mt][dt] = (f32x4){0.f, 0.f, 0.f, 0.f};
    #pragma unroll
    for (int reg = 0; reg < 4; reg++){ mrun[mt][reg] = -1e30f; lrun[mt][reg] = 0.f; }
  }

  unsigned short* pbase = &P_lds[wv * 32 * 64];

  for (int kt = 0; kt < 36; kt++){
    int key0 = kt * 64;
    bf16x8 kf[4][2];
    #pragma unroll
    for (int nt = 0; nt < 4; nt++)
      #pragma unroll
      for (int ks = 0; ks < 2; ks++)
        kf[nt][ks] = *(const bf16x8*)&kg[((size_t)head * NTOK + key0 + nt * 16 + r) * 64 + ks * 32 + g * 8];

    f32x4 s[2][4];
    #pragma unroll
    for (int mt = 0; mt < 2; mt++)
      #pragma unroll
      for (int nt = 0; nt < 4; nt++) s[mt][nt] = (f32x4){0.f, 0.f, 0.f, 0.f};
    #pragma unroll
    for (int mt = 0; mt < 2; mt++)
      #pragma unroll
      for (int nt = 0; nt < 4; nt++){
        s[mt][nt] = __builtin_amdgcn_mfma_f32_16x16x32_bf16(qf[mt][0], kf[nt][0], s[mt][nt], 0, 0, 0);
        s[mt][nt] = __builtin_amdgcn_mfma_f32_16x16x32_bf16(qf[mt][1], kf[nt][1], s[mt][nt], 0, 0, 0);
      }

    // bias: q already scaled, so s + rel_h + rel_w
    int kh[4], kw[4];
    #pragma unroll
    for (int nt = 0; nt < 4; nt++){
      int key = key0 + nt * 16 + r;
      kh[nt] = key / 48; kw[nt] = key % 48;
    }
    #pragma unroll
    for (int mt = 0; mt < 2; mt++)
      #pragma unroll
      for (int reg = 0; reg < 4; reg++){
        const float* rs = &rel_s[(wv * 32 + mt * 16 + g * 4 + reg) * 96];
        #pragma unroll
        for (int nt = 0; nt < 4; nt++)
          s[mt][nt][reg] += rs[kh[nt]] + rs[48 + kw[nt]];
      }

    // online softmax
    #pragma unroll
    for (int mt = 0; mt < 2; mt++)
      #pragma unroll
      for (int reg = 0; reg < 4; reg++){
        float tm = fmaxf(fmaxf(s[mt][0][reg], s[mt][1][reg]), fmaxf(s[mt][2][reg], s[mt][3][reg]));
        tm = fmaxf(tm, __shfl_xor(tm, 1));
        tm = fmaxf(tm, __shfl_xor(tm, 2));
        tm = fmaxf(tm, __shfl_xor(tm, 4));
        tm = fmaxf(tm, __shfl_xor(tm, 8));
        float mold = mrun[mt][reg];
        float mnew = fmaxf(mold, tm);
        float alpha = __expf(mold - mnew);
        mrun[mt][reg] = mnew;
        float ps = 0.f;
        #pragma unroll
        for (int nt = 0; nt < 4; nt++){
          float p = __expf(s[mt][nt][reg] - mnew);
          s[mt][nt][reg] = p;
          ps += p;
        }
        ps += __shfl_xor(ps, 1);
        ps += __shfl_xor(ps, 2);
        ps += __shfl_xor(ps, 4);
        ps += __shfl_xor(ps, 8);
        lrun[mt][reg] = lrun[mt][reg] * alpha + ps;
        #pragma unroll
        for (int dt = 0; dt < 4; dt++) Oa[mt][dt][reg] *= alpha;
      }

    // P -> LDS (swizzled), D-layout write
    #pragma unroll
    for (int mt = 0; mt < 2; mt++)
      #pragma unroll
      for (int reg = 0; reg < 4; reg++){
        int prow = mt * 16 + g * 4 + reg;
        #pragma unroll
        for (int nt = 0; nt < 4; nt++){
          int pcol = nt * 16 + r;
          pbase[prow * 64 + ((((pcol >> 3) ^ (prow & 7)) << 3) | (pcol & 7))] = f2bf(s[mt][nt][reg]);
        }
      }

    // P A-frag read (swizzled) + PV
    bf16x8 pf[2][2];
    #pragma unroll
    for (int mt = 0; mt < 2; mt++)
      #pragma unroll
      for (int ks = 0; ks < 2; ks++){
        int prow = mt * 16 + r;
        pf[mt][ks] = *(const bf16x8*)&pbase[prow * 64 + ((((ks << 2) | g) ^ (prow & 7)) << 3)];
      }
    #pragma unroll
    for (int dt = 0; dt < 4; dt++)
      #pragma unroll
      for (int ks = 0; ks < 2; ks++){
        bf16x8 vf = *(const bf16x8*)&vT[((size_t)head * 64 + dt * 16 + r) * NTOK + key0 + ks * 32 + g * 8];
        #pragma unroll
        for (int mt = 0; mt < 2; mt++)
          Oa[mt][dt] = __builtin_amdgcn_mfma_f32_16x16x32_bf16(pf[mt][ks], vf, Oa[mt][dt], 0, 0, 0);
      }
  }

  #pragma unroll
  for (int mt = 0; mt < 2; mt++)
    #pragma unroll
    for (int reg = 0; reg < 4; reg++){
      int token = qrow + mt * 16 + g * 4 + reg;
      float inv = 1.f / lrun[mt][reg];
      #pragma unroll
      for (int dt = 0; dt < 4; dt++)
        ao[(size_t)token * 768 + head * 64 + dt * 16 + r] = f2bf(Oa[mt][dt][reg] * inv);
    }
}

// ---------------- proj GEMM ----------------
__global__ __launch_bounds__(256) void proj_gemm(
    const unsigned short* __restrict__ ag,   // [2304][768] bf16
    const unsigned short* __restrict__ wg,   // [768][768] bf16
    const float* __restrict__ bias,
    float* __restrict__ out)
{
  __shared__ short As[128*64];
  __shared__ short Bs[128*64];
  const int tid = threadIdx.x;
  const int lane = tid & 63;
  const int wv = tid >> 6;
  const int r = lane & 15, g = lane >> 4;
  const int wm = (wv >> 1) * 64, wn = (wv & 1) * 64;
  const int m0 = blockIdx.y * 128, n0 = blockIdx.x * 128;

  f32x4 acc[4][4];
  #pragma unroll
  for (int i = 0; i < 4; i++)
    #pragma unroll
    for (int j = 0; j < 4; j++) acc[i][j] = (f32x4){0.f, 0.f, 0.f, 0.f};

  for (int k0 = 0; k0 < 768; k0 += 64){
    __syncthreads();
    #pragma unroll
    for (int it = 0; it < 4; it++){
      int f = it * 256 + tid;
      int row = f >> 3, u = f & 7;
      int us = ((u ^ (row & 7)) << 3);
      gload_lds16(ag + (size_t)(m0 + row) * 768 + k0 + us, &As[f * 8]);
      gload_lds16(wg + (size_t)(n0 + row) * 768 + k0 + us, &Bs[f * 8]);
    }
    __syncthreads();
    #pragma unroll
    for (int ks = 0; ks < 2; ks++){
      bf16x8 af[4], bfr[4];
      #pragma unroll
      for (int mt = 0; mt < 4; mt++){
        int row = wm + mt * 16 + r;
        af[mt] = *(const bf16x8*)&As[row * 64 + ((((ks << 2) | g) ^ (r & 7)) << 3)];
      }
      #pragma unroll
      for (int nt = 0; nt < 4; nt++){
        int row = wn + nt * 16 + r;
        bfr[nt] = *(const bf16x8*)&Bs[row * 64 + ((((ks << 2) | g) ^ (r & 7)) << 3)];
      }
      #pragma unroll
      for (int mt = 0; mt < 4; mt++)
        #pragma unroll
        for (int nt = 0; nt < 4; nt++)
          acc[mt][nt] = __builtin_amdgcn_mfma_f32_16x16x32_bf16(af[mt], bfr[nt], acc[mt][nt], 0, 0, 0);
    }
  }

  #pragma unroll
  for (int mt = 0; mt < 4; mt++)
    #pragma unroll
    for (int reg = 0; reg < 4; reg++){
      int row_m = m0 + wm + mt * 16 + g * 4 + reg;
      #pragma unroll
      for (int nt = 0; nt < 4; nt++){
        int col = n0 + wn + nt * 16 + r;
        out[(size_t)row_m * 768 + col] = acc[mt][nt][reg] + bias[col];
      }
    }
}

extern "C" void kernel_launch(void* const* d_in, const int* in_sizes, int n_in,
                              void* d_out, int out_size, void* d_ws, size_t ws_size,
                              hipStream_t stream){
  (void)in_sizes; (void)n_in; (void)out_size; (void)ws_size;
  const float* x      = (const float*)d_in[0];
  const float* qkv_w  = (const float*)d_in[1];
  const float* qkv_b  = (const float*)d_in[2];
  const float* proj_w = (const float*)d_in[3];
  const float* proj_b = (const float*)d_in[4];
  const float* rph    = (const float*)d_in[5];
  const float* rpw    = (const float*)d_in[6];
  const float* Aq     = (const float*)d_in[7];
  const float* Bq     = (const float*)d_in[8];
  const float* Ak     = (const float*)d_in[9];
  const float* Bk     = (const float*)d_in[10];
  const float* Av     = (const float*)d_in[11];
  const float* Bv     = (const float*)d_in[12];

  char* w = (char*)d_ws;
  unsigned short* xb  = (unsigned short*)(w + 0);         // 2304*768 bf16
  unsigned short* wqb = (unsigned short*)(w + 3538944);   // 2304*768 bf16
  unsigned short* wpb = (unsigned short*)(w + 7077888);   //  768*768 bf16
  unsigned short* qb  = (unsigned short*)(w + 8257536);   // 12*2304*64 bf16 (scaled)
  unsigned short* kb  = (unsigned short*)(w + 11796480);  // 12*2304*64 bf16
  unsigned short* vtb = (unsigned short*)(w + 15335424);  // 12*64*2304 bf16
  float* tb           = (float*)(w + 18874368);           // 3*2304*4 f32
  float* rhb          = (float*)(w + 18984960);           // 12*2304*48 f32
  float* rwb          = (float*)(w + 24293376);           // 12*2304*48 f32
  unsigned short* aob = (unsigned short*)(w + 29601792);  // 2304*768 bf16

  cvt_f32_bf16<<<1728, 256, 0, stream>>>(x, xb, 442368);
  cvt_f32_bf16<<<1728, 256, 0, stream>>>(qkv_w, wqb, 442368);
  cvt_f32_bf16<<<576, 256, 0, stream>>>(proj_w, wpb, 147456);
  lora_t_kernel<<<576, 256, 0, stream>>>(x, Aq, Ak, Av, tb);
  qkv_gemm<<<dim3(18, 18), 256, 0, stream>>>(xb, wqb, qkv_b, tb, Bq, Bk, Bv, qb, kb, vtb);
  rel_kernel<<<dim3(48, 12), 256, 0, stream>>>(qb, rph, rpw, rhb, rwb);
  attn_kernel<<<dim3(18, 12), 256, 0, stream>>>(qb, kb, vtb, rhb, rwb, aob);
  proj_gemm<<<dim3(6, 18), 256, 0, stream>>>(aob, wpb, proj_b, (float*)d_out);
}